// Round 1
// baseline (136.349 us; speedup 1.0000x reference)
//
#include <hip/hip_runtime.h>

#define BD 128   // D
#define SL 512   // L
#define NB 4     // B

__device__ __forceinline__ float rcp_fast(float x) { return __builtin_amdgcn_rcpf(x); }

// Kernel 0: transpose Wu, Ww (row-major (out,in)) -> WT[k][o] so the GEMM reads coalesced.
__global__ __launch_bounds__(256) void k_transpose(const float* __restrict__ Wu,
                                                   const float* __restrict__ Ww,
                                                   float* __restrict__ WuT,
                                                   float* __restrict__ WwT) {
    int idx = blockIdx.x * 256 + threadIdx.x;
    if (idx < BD * BD) {
        int k = idx >> 7, o = idx & (BD - 1);
        WuT[idx] = Wu[o * BD + k];
        WwT[idx] = Ww[o * BD + k];
    }
}

// Kernel 1: qu = inp@Wu.T, kw = inp@Ww.T; store Equ = exp(2*qu) TRANSPOSED (d-major),
// Ekw = exp(2*kw) row-major. 8 inp rows per block, thread = output column.
__global__ __launch_bounds__(128) void k_qk(const float* __restrict__ inp,
                                            const float* __restrict__ WuT,
                                            const float* __restrict__ WwT,
                                            float* __restrict__ Equ,
                                            float* __restrict__ Ekw) {
    __shared__ float sx[8][BD];
    const int t  = threadIdx.x;       // output column o
    const int r0 = blockIdx.x * 8;    // global row = b*SL + l
    #pragma unroll
    for (int rr = 0; rr < 8; ++rr)
        sx[rr][t] = inp[(size_t)(r0 + rr) * BD + t];
    __syncthreads();

    float aq[8], aw[8];
    #pragma unroll
    for (int rr = 0; rr < 8; ++rr) { aq[rr] = 0.f; aw[rr] = 0.f; }
    for (int k = 0; k < BD; ++k) {
        float wu = WuT[k * BD + t];   // coalesced
        float ww = WwT[k * BD + t];
        #pragma unroll
        for (int rr = 0; rr < 8; ++rr) {
            float xk = sx[rr][k];     // LDS broadcast
            aq[rr] = fmaf(xk, wu, aq[rr]);
            aw[rr] = fmaf(xk, ww, aw[rr]);
        }
    }
    const int b  = r0 >> 9;           // / SL
    const int l0 = r0 & (SL - 1);
    #pragma unroll
    for (int rr = 0; rr < 8; ++rr) {
        Equ[((size_t)b * BD + t) * SL + (l0 + rr)] = __expf(2.f * aq[rr]); // transposed scatter (small)
        Ekw[(size_t)(r0 + rr) * BD + t]            = __expf(2.f * aw[rr]); // coalesced
    }
}

// Kernel 2: one block per (b, pair of query rows i0,i0+1).
// Phase 1: scores via r = 1/(1 + Equ*Ekw); score = const - 2*sum(wv*r) (const cancels in softmax)
// Phase 2: softmax; Phase 3: out = attn @ inp.
__global__ __launch_bounds__(256) void k_attn(const float* __restrict__ inp,
                                              const float* __restrict__ Wv,
                                              const float* __restrict__ Equ,
                                              const float* __restrict__ Ekw,
                                              float* __restrict__ out,
                                              float* __restrict__ attn) {
    __shared__ float4 s_c[BD];        // (ek0, ek1, wv, 0) -> one b128 broadcast per d
    __shared__ float  s_p[2][SL];
    __shared__ float  s_red[2][4];
    __shared__ float  s_out[2][BD];

    const int t  = threadIdx.x;
    const int b  = blockIdx.x >> 8;          // / (SL/2)
    const int i0 = (blockIdx.x & 255) * 2;

    if (t < BD) {
        float e0 = Ekw[((size_t)b * SL + i0) * BD + t];
        float e1 = Ekw[((size_t)b * SL + i0 + 1) * BD + t];
        float w  = Wv[t];
        s_c[t] = make_float4(e0, e1, w, 0.f);
    }
    __syncthreads();

    // Phase 1: thread t owns j = 2t, 2t+1 for both query rows. Coalesced float2 reads of EquT.
    const float2* equ2 = (const float2*)(Equ + (size_t)b * BD * SL);
    float a00 = 0.f, a01 = 0.f, a10 = 0.f, a11 = 0.f;
    #pragma unroll 4
    for (int d = 0; d < BD; ++d) {
        float2 q = equ2[d * (SL / 2) + t];
        float4 c = s_c[d];
        a00 = fmaf(c.z, rcp_fast(fmaf(q.x, c.x, 1.f)), a00);
        a01 = fmaf(c.z, rcp_fast(fmaf(q.y, c.x, 1.f)), a01);
        a10 = fmaf(c.z, rcp_fast(fmaf(q.x, c.y, 1.f)), a10);
        a11 = fmaf(c.z, rcp_fast(fmaf(q.y, c.y, 1.f)), a11);
    }

    // Phase 2: softmax over j of score = -2*a  (shift-invariant -> reduce min of a)
    float m0 = fminf(a00, a01), m1 = fminf(a10, a11);
    #pragma unroll
    for (int off = 32; off > 0; off >>= 1) {
        m0 = fminf(m0, __shfl_xor(m0, off, 64));
        m1 = fminf(m1, __shfl_xor(m1, off, 64));
    }
    const int wid = t >> 6;
    if ((t & 63) == 0) { s_red[0][wid] = m0; s_red[1][wid] = m1; }
    __syncthreads();
    m0 = fminf(fminf(s_red[0][0], s_red[0][1]), fminf(s_red[0][2], s_red[0][3]));
    m1 = fminf(fminf(s_red[1][0], s_red[1][1]), fminf(s_red[1][2], s_red[1][3]));

    float p00 = __expf(-2.f * (a00 - m0)), p01 = __expf(-2.f * (a01 - m0));
    float p10 = __expf(-2.f * (a10 - m1)), p11 = __expf(-2.f * (a11 - m1));
    float t0 = p00 + p01, t1 = p10 + p11;
    #pragma unroll
    for (int off = 32; off > 0; off >>= 1) {
        t0 += __shfl_xor(t0, off, 64);
        t1 += __shfl_xor(t1, off, 64);
    }
    __syncthreads();   // all reads of s_red(min) done before reuse
    if ((t & 63) == 0) { s_red[0][wid] = t0; s_red[1][wid] = t1; }
    __syncthreads();
    float rs0 = rcp_fast(s_red[0][0] + s_red[0][1] + s_red[0][2] + s_red[0][3]);
    float rs1 = rcp_fast(s_red[1][0] + s_red[1][1] + s_red[1][2] + s_red[1][3]);

    float n00 = p00 * rs0, n01 = p01 * rs0, n10 = p10 * rs1, n11 = p11 * rs1;
    float2* at0 = (float2*)(attn + ((size_t)b * SL + i0) * SL);
    float2* at1 = (float2*)(attn + ((size_t)b * SL + i0 + 1) * SL);
    at0[t] = make_float2(n00, n01);
    at1[t] = make_float2(n10, n11);
    s_p[0][2 * t] = n00; s_p[0][2 * t + 1] = n01;
    s_p[1][2 * t] = n10; s_p[1][2 * t + 1] = n11;
    __syncthreads();

    // Phase 3: out[b,i,d] = sum_j attn[j] * inp[b,j,d]; thread = (d, j-half)
    const int dd = t & (BD - 1), jh = t >> 7;
    const float* inpb = inp + (size_t)b * SL * BD;
    float o0 = 0.f, o1 = 0.f;
    #pragma unroll 4
    for (int jj = 0; jj < SL / 2; ++jj) {
        int j = jh * (SL / 2) + jj;
        float x = inpb[(size_t)j * BD + dd];   // coalesced
        o0 = fmaf(s_p[0][j], x, o0);           // LDS broadcast
        o1 = fmaf(s_p[1][j], x, o1);
    }
    if (jh) { s_out[0][dd] = o0; s_out[1][dd] = o1; }
    __syncthreads();
    if (!jh) {
        out[((size_t)b * SL + i0) * BD + dd]     = o0 + s_out[0][dd];
        out[((size_t)b * SL + i0 + 1) * BD + dd] = o1 + s_out[1][dd];
    }
}

extern "C" void kernel_launch(void* const* d_in, const int* in_sizes, int n_in,
                              void* d_out, int out_size, void* d_ws, size_t ws_size,
                              hipStream_t stream) {
    const float* inp = (const float*)d_in[0];
    const float* Wu  = (const float*)d_in[1];
    const float* Ww  = (const float*)d_in[2];
    const float* Wv  = (const float*)d_in[3];

    float* out  = (float*)d_out;
    float* attn = out + (size_t)NB * SL * BD;   // outputs concatenated: out (B,L,D) then attn (B,L,L)

    float* ws  = (float*)d_ws;
    float* WuT = ws;
    float* WwT = WuT + BD * BD;
    float* Equ = WwT + BD * BD;                  // (B, D, L) transposed, exp(2*qu)
    float* Ekw = Equ + (size_t)NB * BD * SL;     // (B, L, D), exp(2*kw)

    k_transpose<<<(BD * BD + 255) / 256, 256, 0, stream>>>(Wu, Ww, WuT, WwT);
    k_qk<<<NB * SL / 8, 128, 0, stream>>>(inp, WuT, WwT, Equ, Ekw);
    k_attn<<<NB * SL / 2, 256, 0, stream>>>(inp, Wv, Equ, Ekw, out, attn);
}

// Round 2
// 100.335 us; speedup vs baseline: 1.3589x; 1.3589x over previous
//
#include <hip/hip_runtime.h>

#define BD 128   // D
#define SL 512   // L
#define NB 4     // B

__device__ __forceinline__ float rcp_fast(float x) { return __builtin_amdgcn_rcpf(x); }

// K1: qu = inp@Wu.T, kw = inp@Ww.T with in-block LDS transpose staging of W.
// Grid 512 blocks x 256 threads; block handles 4 rows; threads t<128 -> qu col o,
// t>=128 -> kw col o. Writes Equ=exp(2qu) TRANSPOSED (b,d,l) and Ekw=exp(2kw) (b,l,d).
__global__ __launch_bounds__(256, 2) void k_qk(const float* __restrict__ inp,
                                               const float* __restrict__ Wu,
                                               const float* __restrict__ Ww,
                                               float* __restrict__ Equ,
                                               float* __restrict__ Ekw) {
    __shared__ float sx[4][BD];            // 4 input rows
    __shared__ float swT[2][32][BD + 1];   // [mat][kk][o], transposed W chunk, padded

    const int t  = threadIdx.x;
    const int r0 = blockIdx.x * 4;         // global row = b*SL + l
    const int b  = r0 >> 9;
    const int l0 = r0 & (SL - 1);

    #pragma unroll
    for (int h = 0; h < 2; ++h) {
        int idx = h * 256 + t;             // 0..511
        sx[idx >> 7][idx & 127] = inp[(size_t)(r0 + (idx >> 7)) * BD + (idx & 127)];
    }

    const int m = t >> 7, o = t & 127;
    float acc[4] = {0.f, 0.f, 0.f, 0.f};

    for (int k0 = 0; k0 < BD; k0 += 32) {
        __syncthreads();                   // protects sx (first iter) + swT reuse
        #pragma unroll
        for (int i = 0; i < 32; ++i) {
            int idx = i * 256 + t;         // 0..8191
            int mm  = idx >> 12;
            int rem = idx & 4095;
            int oo  = rem >> 5, kk = rem & 31;
            swT[mm][kk][oo] = (mm ? Ww : Wu)[oo * BD + k0 + kk];   // coalesced-ish 128B runs
        }
        __syncthreads();
        #pragma unroll
        for (int kk = 0; kk < 32; kk += 4) {
            float w0 = swT[m][kk + 0][o];
            float w1 = swT[m][kk + 1][o];
            float w2 = swT[m][kk + 2][o];
            float w3 = swT[m][kk + 3][o];
            #pragma unroll
            for (int rr = 0; rr < 4; ++rr) {
                float4 x = *(const float4*)&sx[rr][k0 + kk];
                acc[rr] = fmaf(x.x, w0, acc[rr]);
                acc[rr] = fmaf(x.y, w1, acc[rr]);
                acc[rr] = fmaf(x.z, w2, acc[rr]);
                acc[rr] = fmaf(x.w, w3, acc[rr]);
            }
        }
    }

    if (m == 0) {
        #pragma unroll
        for (int rr = 0; rr < 4; ++rr)     // transposed scatter (small: 1MB total)
            Equ[((size_t)b * BD + o) * SL + l0 + rr] = __expf(2.f * acc[rr]);
    } else {
        #pragma unroll
        for (int rr = 0; rr < 4; ++rr)     // coalesced
            Ekw[(size_t)(r0 + rr) * BD + o] = __expf(2.f * acc[rr]);
    }
}

// K2: one block per (b, 4 query rows). score = C - 2*sum_d wv/(1+Equ[j,d]*Ekw[i,d]);
// softmax over j; out = attn @ inp. Grid 512 x 256.
__global__ __launch_bounds__(256, 2) void k_attn(const float* __restrict__ inp,
                                                 const float* __restrict__ Wv,
                                                 const float* __restrict__ Equ,
                                                 const float* __restrict__ Ekw,
                                                 float* __restrict__ out,
                                                 float* __restrict__ attn) {
    __shared__ float4 s_ce[BD];            // ekw for the 4 i-rows, per d
    __shared__ float  s_wv[BD];
    __shared__ float4 s_p[SL];             // attn weights, 4 rows packed per j
    __shared__ float  s_fin[4][4][BD];     // [jh][i][d] phase-3 partials
    __shared__ float  s_red[4][4];

    const int t  = threadIdx.x;
    const int b  = blockIdx.x >> 7;
    const int i0 = (blockIdx.x & 127) * 4;

    if (t < BD) {
        const float* ek = Ekw + ((size_t)b * SL + i0) * BD + t;
        s_ce[t] = make_float4(ek[0], ek[BD], ek[2 * BD], ek[3 * BD]);
        s_wv[t] = Wv[t];
    }
    __syncthreads();

    // Phase 1: thread t owns j = 2t, 2t+1 for 4 query rows -> 8 independent chains.
    const float2* equ2 = (const float2*)(Equ + (size_t)b * BD * SL);
    float a[4][2];
    #pragma unroll
    for (int i = 0; i < 4; ++i) { a[i][0] = 0.f; a[i][1] = 0.f; }

    #pragma unroll 4
    for (int d = 0; d < BD; ++d) {
        float2 q = equ2[d * (SL / 2) + t];   // coalesced 512B/wave
        float4 e = s_ce[d];                  // LDS broadcast
        float  w = s_wv[d];
        a[0][0] = fmaf(w, rcp_fast(fmaf(q.x, e.x, 1.f)), a[0][0]);
        a[0][1] = fmaf(w, rcp_fast(fmaf(q.y, e.x, 1.f)), a[0][1]);
        a[1][0] = fmaf(w, rcp_fast(fmaf(q.x, e.y, 1.f)), a[1][0]);
        a[1][1] = fmaf(w, rcp_fast(fmaf(q.y, e.y, 1.f)), a[1][1]);
        a[2][0] = fmaf(w, rcp_fast(fmaf(q.x, e.z, 1.f)), a[2][0]);
        a[2][1] = fmaf(w, rcp_fast(fmaf(q.y, e.z, 1.f)), a[2][1]);
        a[3][0] = fmaf(w, rcp_fast(fmaf(q.x, e.w, 1.f)), a[3][0]);
        a[3][1] = fmaf(w, rcp_fast(fmaf(q.y, e.w, 1.f)), a[3][1]);
    }

    // Phase 2: softmax over j of score = -2a (shift-invariant -> min over a).
    const int wid = t >> 6;
    float mn[4];
    #pragma unroll
    for (int i = 0; i < 4; ++i) mn[i] = fminf(a[i][0], a[i][1]);
    #pragma unroll
    for (int off = 32; off > 0; off >>= 1) {
        #pragma unroll
        for (int i = 0; i < 4; ++i) mn[i] = fminf(mn[i], __shfl_xor(mn[i], off, 64));
    }
    if ((t & 63) == 0) {
        #pragma unroll
        for (int i = 0; i < 4; ++i) s_red[i][wid] = mn[i];
    }
    __syncthreads();
    #pragma unroll
    for (int i = 0; i < 4; ++i)
        mn[i] = fminf(fminf(s_red[i][0], s_red[i][1]), fminf(s_red[i][2], s_red[i][3]));

    float p[4][2], sm[4];
    #pragma unroll
    for (int i = 0; i < 4; ++i) {
        p[i][0] = __expf(-2.f * (a[i][0] - mn[i]));
        p[i][1] = __expf(-2.f * (a[i][1] - mn[i]));
        sm[i]   = p[i][0] + p[i][1];
    }
    #pragma unroll
    for (int off = 32; off > 0; off >>= 1) {
        #pragma unroll
        for (int i = 0; i < 4; ++i) sm[i] += __shfl_xor(sm[i], off, 64);
    }
    __syncthreads();                        // finish reads of s_red before reuse
    if ((t & 63) == 0) {
        #pragma unroll
        for (int i = 0; i < 4; ++i) s_red[i][wid] = sm[i];
    }
    __syncthreads();
    float rs[4];
    #pragma unroll
    for (int i = 0; i < 4; ++i)
        rs[i] = rcp_fast(s_red[i][0] + s_red[i][1] + s_red[i][2] + s_red[i][3]);

    float n0[4], n1[4];
    #pragma unroll
    for (int i = 0; i < 4; ++i) { n0[i] = p[i][0] * rs[i]; n1[i] = p[i][1] * rs[i]; }
    #pragma unroll
    for (int i = 0; i < 4; ++i) {
        float2* at = (float2*)(attn + ((size_t)b * SL + i0 + i) * SL);
        at[t] = make_float2(n0[i], n1[i]);  // coalesced
    }
    s_p[2 * t]     = make_float4(n0[0], n0[1], n0[2], n0[3]);
    s_p[2 * t + 1] = make_float4(n1[0], n1[1], n1[2], n1[3]);
    __syncthreads();

    // Phase 3: out[b,i,d] = sum_j attn * inp. Threads = (64 d-pairs, 4 j-quarters).
    const int dv = t & 63, jh = t >> 6;
    const float2* inp2 = (const float2*)(inp + (size_t)b * SL * BD);
    float o0[4] = {0.f, 0.f, 0.f, 0.f}, o1[4] = {0.f, 0.f, 0.f, 0.f};
    #pragma unroll 4
    for (int jj = 0; jj < SL / 4; ++jj) {
        int j = jh * (SL / 4) + jj;
        float2 x  = inp2[j * (BD / 2) + dv];  // coalesced 512B/wave
        float4 p4 = s_p[j];                   // b128 broadcast (wave-uniform j)
        o0[0] = fmaf(p4.x, x.x, o0[0]);  o1[0] = fmaf(p4.x, x.y, o1[0]);
        o0[1] = fmaf(p4.y, x.x, o0[1]);  o1[1] = fmaf(p4.y, x.y, o1[1]);
        o0[2] = fmaf(p4.z, x.x, o0[2]);  o1[2] = fmaf(p4.z, x.y, o1[2]);
        o0[3] = fmaf(p4.w, x.x, o0[3]);  o1[3] = fmaf(p4.w, x.y, o1[3]);
    }
    #pragma unroll
    for (int i = 0; i < 4; ++i) {
        s_fin[jh][i][2 * dv]     = o0[i];     // b64, 2-way = free
        s_fin[jh][i][2 * dv + 1] = o1[i];
    }
    __syncthreads();
    #pragma unroll
    for (int h = 0; h < 2; ++h) {
        int id = h * 256 + t;
        int i = id >> 7, d = id & 127;
        float s = s_fin[0][i][d] + s_fin[1][i][d] + s_fin[2][i][d] + s_fin[3][i][d];
        out[((size_t)b * SL + i0 + i) * BD + d] = s;   // coalesced
    }
}

extern "C" void kernel_launch(void* const* d_in, const int* in_sizes, int n_in,
                              void* d_out, int out_size, void* d_ws, size_t ws_size,
                              hipStream_t stream) {
    const float* inp = (const float*)d_in[0];
    const float* Wu  = (const float*)d_in[1];
    const float* Ww  = (const float*)d_in[2];
    const float* Wv  = (const float*)d_in[3];

    float* out  = (float*)d_out;
    float* attn = out + (size_t)NB * SL * BD;   // out (B,L,D) then attn (B,L,L)

    float* ws  = (float*)d_ws;
    float* Equ = ws;                            // (B, D, L) exp(2*qu), transposed
    float* Ekw = Equ + (size_t)NB * BD * SL;    // (B, L, D) exp(2*kw)

    k_qk<<<NB * SL / 4, 256, 0, stream>>>(inp, Wu, Ww, Equ, Ekw);
    k_attn<<<NB * SL / 4, 256, 0, stream>>>(inp, Wv, Equ, Ekw, out, attn);
}